// Round 2
// 619.412 us; speedup vs baseline: 1.0647x; 1.0647x over previous
//
#include <hip/hip_runtime.h>
#include <stdint.h>

#define IN_F 4096
#define OUT_F 4096

typedef __attribute__((ext_vector_type(8))) __bf16 bf16x8;
typedef __attribute__((ext_vector_type(8))) short short8;
typedef __attribute__((ext_vector_type(4))) float f32x4;

struct SelState {
  unsigned int hist[3 * 2048];
  unsigned int prefix;     // accumulates selected bin bits; after round 2 = threshold bit pattern
  unsigned int remaining;  // k remaining within current prefix
  unsigned int count;
  float sum;
  float scale;
};

__device__ __forceinline__ unsigned short f2bf_rne(unsigned int u) {
  // round-to-nearest-even fp32 -> bf16 (inputs are finite, no NaN handling needed)
  return (unsigned short)((u + 0x7FFFu + ((u >> 16) & 1u)) >> 16);
}

// cast x to bf16; block 0 also zeroes/initializes SelState (replaces init_kernel;
// stream order guarantees all of this completes before hist_kernel starts).
__global__ void cast_x_kernel(const float4* __restrict__ x, ushort4* __restrict__ xb, int n4,
                              SelState* st, unsigned int k) {
  int t = threadIdx.x;
  if (blockIdx.x == 0) {
    for (int i = t; i < 3 * 2048; i += 256) st->hist[i] = 0;
    if (t == 0) {
      st->prefix = 0;
      st->remaining = k;
      st->count = 0;
      st->sum = 0.0f;
    }
  }
  int i = blockIdx.x * blockDim.x + t;
  int stride = gridDim.x * blockDim.x;
  for (; i < n4; i += stride) {
    float4 v = x[i];
    ushort4 o;
    o.x = f2bf_rne(__float_as_uint(v.x));
    o.y = f2bf_rne(__float_as_uint(v.y));
    o.z = f2bf_rne(__float_as_uint(v.z));
    o.w = f2bf_rne(__float_as_uint(v.w));
    xb[i] = o;
  }
}

// Radix-select histogram. round 0: bits[30:20] (2048 bins); round 1: bits[19:10]
// among prefix matches (1024 bins); round 2: bits[9:0] (1024 bins).
__global__ void hist_kernel(const float4* __restrict__ w, int n4, SelState* st, int round) {
  __shared__ unsigned int lh[2048];
  int nbins = (round == 0) ? 2048 : 1024;
  int t = threadIdx.x;
  for (int i = t; i < nbins; i += 256) lh[i] = 0;
  __syncthreads();
  unsigned int prefix = st->prefix;
  int i = blockIdx.x * blockDim.x + t;
  int stride = gridDim.x * blockDim.x;
  for (; i < n4; i += stride) {
    float4 v = w[i];
#pragma unroll
    for (int c = 0; c < 4; ++c) {
      unsigned int u = __float_as_uint(((const float*)&v)[c]) & 0x7FFFFFFFu;
      if (round == 0) {
        atomicAdd(&lh[u >> 20], 1u);
      } else if (round == 1) {
        if ((u >> 20) == prefix) atomicAdd(&lh[(u >> 10) & 1023u], 1u);
      } else {
        if ((u >> 10) == prefix) atomicAdd(&lh[u & 1023u], 1u);
      }
    }
  }
  __syncthreads();
  unsigned int* gh = st->hist + round * 2048;
  for (int b = t; b < nbins; b += 256) {
    unsigned int c = lh[b];
    if (c) atomicAdd(&gh[b], c);
  }
}

// Single block: find bin containing the remaining-th smallest; update prefix/remaining.
__global__ void scan_kernel(SelState* st, int round) {
  __shared__ unsigned int part[256];
  __shared__ unsigned int sh[2];
  __shared__ unsigned int segbins[8];
  int t = threadIdx.x;
  int nbins = (round == 0) ? 2048 : 1024;
  int per = nbins / 256;
  unsigned int* h = st->hist + round * 2048;
  unsigned int s = 0;
  for (int i = 0; i < per; ++i) s += h[t * per + i];
  part[t] = s;
  __syncthreads();
  if (t == 0) {
    unsigned int rem = st->remaining;
    int seg = 255;
    for (int i = 0; i < 256; ++i) {
      if (part[i] >= rem) { seg = i; break; }
      rem -= part[i];
    }
    sh[0] = (unsigned int)seg;
    sh[1] = rem;
  }
  __syncthreads();
  int seg = (int)sh[0];
  if (t < per) segbins[t] = h[seg * per + t];
  __syncthreads();
  if (t == 0) {
    unsigned int rem = sh[1];
    int b = seg * per + per - 1;
    for (int i = 0; i < per; ++i) {
      unsigned int c = segbins[i];
      if (c >= rem) { b = seg * per + i; break; }
      rem -= c;
    }
    st->remaining = rem;
    int width = (round == 0) ? 11 : 10;
    st->prefix = (st->prefix << width) | (unsigned int)b;
  }
}

// Ternary-quantize weights to bf16 {-1,0,+1}; fused sum(|w|*mask)/count reduction.
__global__ void quant_kernel(const float4* __restrict__ w, ushort4* __restrict__ wt,
                             int n4, SelState* st) {
  unsigned int thr = st->prefix;
  int t = threadIdx.x;
  float lsum = 0.0f;
  unsigned int lcnt = 0;
  int i = blockIdx.x * blockDim.x + t;
  int stride = gridDim.x * blockDim.x;
  for (; i < n4; i += stride) {
    float4 v = w[i];
    ushort4 o;
    unsigned short* op = (unsigned short*)&o;
#pragma unroll
    for (int c = 0; c < 4; ++c) {
      unsigned int u = __float_as_uint(((const float*)&v)[c]);
      unsigned int a = u & 0x7FFFFFFFu;
      bool keep = a > thr;  // strict >, bit-exact vs reference
      op[c] = keep ? (unsigned short)(0x3F80u | ((u >> 16) & 0x8000u)) : (unsigned short)0;
      if (keep) {
        lsum += __uint_as_float(a);
        lcnt++;
      }
    }
    wt[i] = o;
  }
#pragma unroll
  for (int off = 32; off > 0; off >>= 1) {
    lsum += __shfl_down(lsum, off);
    lcnt += __shfl_down(lcnt, off);
  }
  __shared__ float ssum[4];
  __shared__ unsigned int scnt[4];
  int wave = t >> 6, lane = t & 63;
  if (lane == 0) { ssum[wave] = lsum; scnt[wave] = lcnt; }
  __syncthreads();
  if (t == 0) {
    float fs = ssum[0] + ssum[1] + ssum[2] + ssum[3];
    unsigned int fc = scnt[0] + scnt[1] + scnt[2] + scnt[3];
    atomicAdd(&st->sum, fs);
    atomicAdd(&st->count, fc);
  }
}

__device__ __forceinline__ void async_copy16(const unsigned short* g, unsigned short* l) {
  __builtin_amdgcn_global_load_lds(
      (const __attribute__((address_space(1))) void*)g,
      (__attribute__((address_space(3))) void*)l, 16, 0, 0);
}

// 256x256-tile GEMM, BK=32, 4 rotating LDS buffers (128 KiB), counted-vmcnt
// pipeline: 3 tiles prefetched ahead, s_waitcnt vmcnt(8) per iteration (never
// drain to 0 in the main loop), one raw s_barrier per iteration. No LDS
// swizzle needed: BK=32 rows are 64 B, so a wave's fragment read (16 rows x 4
// quad slots) is a contiguous 1 KiB block with 64 distinct 16B chunks ->
// uniform bank coverage (the 128-B-row conflict of the old BK=64 layout is
// structurally absent). 8 waves (2Mx4N), 128x64 output per wave.
// C[m][n] = scale * sum_k A[m][k]*B[n][k] + bias[n].
__global__ __launch_bounds__(512, 2)
void gemm_kernel(const unsigned short* __restrict__ A,
                 const unsigned short* __restrict__ B,
                 const float* __restrict__ bias,
                 const SelState* __restrict__ st,
                 float* __restrict__ C, int N) {
  constexpr int K = IN_F;
  constexpr int NT = K / 32;  // 128 K-tiles
  __shared__ __align__(16) unsigned short As[4][256 * 32];
  __shared__ __align__(16) unsigned short Bs[4][256 * 32];

  const int tid = threadIdx.x;
  const int wave = tid >> 6, lane = tid & 63;
  const int wm = wave >> 2, wn = wave & 3;   // 2x4 wave grid
  const int l16 = lane & 15, quad = lane >> 4;

  const int rowBase = blockIdx.y * 256;
  const int colBase = blockIdx.x * 256;
  const unsigned short* Ag = A + (size_t)rowBase * K;
  const unsigned short* Bg = B + (size_t)colBase * K;

  // Staging: per tile 4 issues x 512 threads x 16B = 256 rows x 64 B, linear.
  // Chunk id g: row g>>2, 16B slot g&3. LDS dest chunk g at byte offset g*16
  // (wave-uniform base + lane*16, as global_load_lds requires).
  const int g0 = tid;
  const int g1 = 512 + tid;
  const unsigned short* pA0 = Ag + (size_t)(g0 >> 2) * K + (g0 & 3) * 8;
  const unsigned short* pA1 = Ag + (size_t)(g1 >> 2) * K + (g1 & 3) * 8;
  const unsigned short* pB0 = Bg + (size_t)(g0 >> 2) * K + (g0 & 3) * 8;
  const unsigned short* pB1 = Bg + (size_t)(g1 >> 2) * K + (g1 & 3) * 8;

  const int aoff = (wm * 128 + l16) * 32 + quad * 8;
  const int boff = (wn * 64 + l16) * 32 + quad * 8;

  f32x4 acc[8][4];
#pragma unroll
  for (int i = 0; i < 8; ++i)
#pragma unroll
    for (int j = 0; j < 4; ++j) acc[i][j] = {0.0f, 0.0f, 0.0f, 0.0f};

#define STAGE(buf, t) do {                                   \
    int ko = (t) * 32;                                       \
    async_copy16(pA0 + ko, &As[(buf)][g0 * 8]);              \
    async_copy16(pA1 + ko, &As[(buf)][g1 * 8]);              \
    async_copy16(pB0 + ko, &Bs[(buf)][g0 * 8]);              \
    async_copy16(pB1 + ko, &Bs[(buf)][g1 * 8]);              \
  } while (0)

  // KBODY: wait(tile t landed for THIS wave; my ds_reads of buf (u+3)&3 from
  // iter t-1 drained) -> barrier (now tile t landed for ALL waves, and buf
  // (u+3)&3 is not being read by anyone) -> prefetch tile t+3 into it ->
  // fragment ds_reads -> MFMA cluster under setprio(1).
#define KBODY(t, u, VMASM, DOSTAGE) do {                                        \
    asm volatile(VMASM ::: "memory");                                           \
    __builtin_amdgcn_s_barrier();                                               \
    asm volatile("" ::: "memory");                                              \
    if (DOSTAGE) STAGE(((u) + 3) & 3, (t) + 3);                                 \
    const unsigned short* Ab = As[(u)];                                         \
    const unsigned short* Bb = Bs[(u)];                                         \
    bf16x8 af[8];                                                               \
    bf16x8 bfr[4];                                                              \
    _Pragma("unroll")                                                           \
    for (int i = 0; i < 8; ++i)                                                 \
      af[i] = __builtin_bit_cast(bf16x8, *(const short8*)(Ab + aoff + i * 512));\
    _Pragma("unroll")                                                           \
    for (int j = 0; j < 4; ++j)                                                 \
      bfr[j] = __builtin_bit_cast(bf16x8, *(const short8*)(Bb + boff + j * 512));\
    __builtin_amdgcn_s_setprio(1);                                              \
    _Pragma("unroll")                                                           \
    for (int i = 0; i < 8; ++i)                                                 \
      _Pragma("unroll")                                                         \
      for (int j = 0; j < 4; ++j)                                               \
        acc[i][j] = __builtin_amdgcn_mfma_f32_16x16x32_bf16(af[i], bfr[j],      \
                                                            acc[i][j], 0, 0, 0);\
    __builtin_amdgcn_s_setprio(0);                                              \
  } while (0)

  // Prologue: 3 tiles in flight (12 outstanding loads per thread).
  STAGE(0, 0);
  STAGE(1, 1);
  STAGE(2, 2);

  // Steady state: 12 outstanding -> vmcnt(8) proves the oldest tile landed.
  for (int tt = 0; tt <= NT - 8; tt += 4) {
    KBODY(tt + 0, 0, "s_waitcnt vmcnt(8) lgkmcnt(0)", true);
    KBODY(tt + 1, 1, "s_waitcnt vmcnt(8) lgkmcnt(0)", true);
    KBODY(tt + 2, 2, "s_waitcnt vmcnt(8) lgkmcnt(0)", true);
    KBODY(tt + 3, 3, "s_waitcnt vmcnt(8) lgkmcnt(0)", true);
  }
  // Tail: stage last tile, then drain 8 -> 4 -> 0.
  KBODY(NT - 4, 0, "s_waitcnt vmcnt(8) lgkmcnt(0)", true);
  KBODY(NT - 3, 1, "s_waitcnt vmcnt(8) lgkmcnt(0)", false);
  KBODY(NT - 2, 2, "s_waitcnt vmcnt(4) lgkmcnt(0)", false);
  KBODY(NT - 1, 3, "s_waitcnt vmcnt(0) lgkmcnt(0)", false);

#undef KBODY
#undef STAGE

  // scale computed inline (replaces finalize_kernel; identical fp32 division).
  unsigned int cnt = st->count;
  float scale = st->sum / (float)(cnt ? cnt : 1u);
  float bv[4];
#pragma unroll
  for (int j = 0; j < 4; ++j) bv[j] = bias[colBase + wn * 64 + j * 16 + l16];
#pragma unroll
  for (int i = 0; i < 8; ++i) {
    int row0 = rowBase + wm * 128 + i * 16 + quad * 4;
#pragma unroll
    for (int j = 0; j < 4; ++j) {
      int col = colBase + wn * 64 + j * 16 + l16;
#pragma unroll
      for (int r = 0; r < 4; ++r) {
        C[(size_t)(row0 + r) * N + col] = scale * acc[i][j][r] + bv[j];
      }
    }
  }
}

extern "C" void kernel_launch(void* const* d_in, const int* in_sizes, int n_in,
                              void* d_out, int out_size, void* d_ws, size_t ws_size,
                              hipStream_t stream) {
  const float* x = (const float*)d_in[0];
  const float* w = (const float*)d_in[1];
  const float* bias = (const float*)d_in[2];
  float* out = (float*)d_out;
  const int K = IN_F, N = OUT_F;
  const int n_w = in_sizes[1];            // 4096*4096
  const int n_x = in_sizes[0];            // 4*2048*4096
  const int M = n_x / K;                  // 8192
  const unsigned int k = (unsigned int)(n_w / 2);  // int(n * 0.5), 1-indexed kth

  char* ws = (char*)d_ws;
  SelState* st = (SelState*)ws;
  unsigned short* wt = (unsigned short*)(ws + 65536);                              // 32 MB
  unsigned short* xb = (unsigned short*)(ws + 65536 + (size_t)N * K * 2);          // 64 MB

  hipLaunchKernelGGL(cast_x_kernel, dim3(4096), dim3(256), 0, stream,
                     (const float4*)x, (ushort4*)xb, n_x / 4, st, k);
  for (int r = 0; r < 3; ++r) {
    hipLaunchKernelGGL(hist_kernel, dim3(1024), dim3(256), 0, stream,
                       (const float4*)w, n_w / 4, st, r);
    hipLaunchKernelGGL(scan_kernel, dim3(1), dim3(256), 0, stream, st, r);
  }
  hipLaunchKernelGGL(quant_kernel, dim3(1024), dim3(256), 0, stream,
                     (const float4*)w, (ushort4*)wt, n_w / 4, st);
  hipLaunchKernelGGL(gemm_kernel, dim3(N / 256, M / 256), dim3(512), 0, stream,
                     xb, wt, bias, st, out, N);
}

// Round 3
// 603.350 us; speedup vs baseline: 1.0931x; 1.0266x over previous
//
#include <hip/hip_runtime.h>
#include <stdint.h>

#define IN_F 4096
#define OUT_F 4096

typedef __attribute__((ext_vector_type(8))) __bf16 bf16x8;
typedef __attribute__((ext_vector_type(8))) short short8;
typedef __attribute__((ext_vector_type(4))) float f32x4;

struct SelState {
  unsigned int hist[3 * 2048];
  unsigned int prefix;     // accumulates selected bin bits; after round 2 = threshold bit pattern
  unsigned int remaining;  // k remaining within current prefix
  unsigned int count;
  float sum;
  float scale;
};

__device__ __forceinline__ unsigned short f2bf_rne(unsigned int u) {
  // round-to-nearest-even fp32 -> bf16 (inputs are finite, no NaN handling needed)
  return (unsigned short)((u + 0x7FFFu + ((u >> 16) & 1u)) >> 16);
}

// cast x to bf16; block 0 also zeroes/initializes SelState (replaces init_kernel;
// stream order guarantees all of this completes before hist_kernel starts).
__global__ void cast_x_kernel(const float4* __restrict__ x, ushort4* __restrict__ xb, int n4,
                              SelState* st, unsigned int k) {
  int t = threadIdx.x;
  if (blockIdx.x == 0) {
    for (int i = t; i < 3 * 2048; i += 256) st->hist[i] = 0;
    if (t == 0) {
      st->prefix = 0;
      st->remaining = k;
      st->count = 0;
      st->sum = 0.0f;
    }
  }
  int i = blockIdx.x * blockDim.x + t;
  int stride = gridDim.x * blockDim.x;
  for (; i < n4; i += stride) {
    float4 v = x[i];
    ushort4 o;
    o.x = f2bf_rne(__float_as_uint(v.x));
    o.y = f2bf_rne(__float_as_uint(v.y));
    o.z = f2bf_rne(__float_as_uint(v.z));
    o.w = f2bf_rne(__float_as_uint(v.w));
    xb[i] = o;
  }
}

// Radix-select histogram. round 0: bits[30:20] (2048 bins); round 1: bits[19:10]
// among prefix matches (1024 bins); round 2: bits[9:0] (1024 bins).
// Per-wave replicated sub-histograms (4x): uniform-distributed weights put ~50%
// of elements in the top few exponent bins, so same-address LDS atomic
// serialization dominates round 0; replication cuts inter-wave contention 4x.
__global__ void hist_kernel(const float4* __restrict__ w, int n4, SelState* st, int round) {
  __shared__ unsigned int lh[4 * 2048];
  int nbins = (round == 0) ? 2048 : 1024;
  int t = threadIdx.x;
  int wbase = (t >> 6) * nbins;
  for (int i = t; i < 4 * nbins; i += 256) lh[i] = 0;
  __syncthreads();
  unsigned int prefix = st->prefix;
  int i = blockIdx.x * blockDim.x + t;
  int stride = gridDim.x * blockDim.x;
  for (; i < n4; i += stride) {
    float4 v = w[i];
#pragma unroll
    for (int c = 0; c < 4; ++c) {
      unsigned int u = __float_as_uint(((const float*)&v)[c]) & 0x7FFFFFFFu;
      if (round == 0) {
        atomicAdd(&lh[wbase + (u >> 20)], 1u);
      } else if (round == 1) {
        if ((u >> 20) == prefix) atomicAdd(&lh[wbase + ((u >> 10) & 1023u)], 1u);
      } else {
        if ((u >> 10) == prefix) atomicAdd(&lh[wbase + (u & 1023u)], 1u);
      }
    }
  }
  __syncthreads();
  unsigned int* gh = st->hist + round * 2048;
  for (int b = t; b < nbins; b += 256) {
    unsigned int c = lh[b] + lh[nbins + b] + lh[2 * nbins + b] + lh[3 * nbins + b];
    if (c) atomicAdd(&gh[b], c);
  }
}

// Single block: find bin containing the remaining-th smallest; update prefix/remaining.
__global__ void scan_kernel(SelState* st, int round) {
  __shared__ unsigned int part[256];
  __shared__ unsigned int sh[2];
  __shared__ unsigned int segbins[8];
  int t = threadIdx.x;
  int nbins = (round == 0) ? 2048 : 1024;
  int per = nbins / 256;
  unsigned int* h = st->hist + round * 2048;
  unsigned int s = 0;
  for (int i = 0; i < per; ++i) s += h[t * per + i];
  part[t] = s;
  __syncthreads();
  if (t == 0) {
    unsigned int rem = st->remaining;
    int seg = 255;
    for (int i = 0; i < 256; ++i) {
      if (part[i] >= rem) { seg = i; break; }
      rem -= part[i];
    }
    sh[0] = (unsigned int)seg;
    sh[1] = rem;
  }
  __syncthreads();
  int seg = (int)sh[0];
  if (t < per) segbins[t] = h[seg * per + t];
  __syncthreads();
  if (t == 0) {
    unsigned int rem = sh[1];
    int b = seg * per + per - 1;
    for (int i = 0; i < per; ++i) {
      unsigned int c = segbins[i];
      if (c >= rem) { b = seg * per + i; break; }
      rem -= c;
    }
    st->remaining = rem;
    int width = (round == 0) ? 11 : 10;
    st->prefix = (st->prefix << width) | (unsigned int)b;
  }
}

// Ternary-quantize weights to bf16 {-1,0,+1}; fused sum(|w|*mask)/count reduction.
__global__ void quant_kernel(const float4* __restrict__ w, ushort4* __restrict__ wt,
                             int n4, SelState* st) {
  unsigned int thr = st->prefix;
  int t = threadIdx.x;
  float lsum = 0.0f;
  unsigned int lcnt = 0;
  int i = blockIdx.x * blockDim.x + t;
  int stride = gridDim.x * blockDim.x;
  for (; i < n4; i += stride) {
    float4 v = w[i];
    ushort4 o;
    unsigned short* op = (unsigned short*)&o;
#pragma unroll
    for (int c = 0; c < 4; ++c) {
      unsigned int u = __float_as_uint(((const float*)&v)[c]);
      unsigned int a = u & 0x7FFFFFFFu;
      bool keep = a > thr;  // strict >, bit-exact vs reference
      op[c] = keep ? (unsigned short)(0x3F80u | ((u >> 16) & 0x8000u)) : (unsigned short)0;
      if (keep) {
        lsum += __uint_as_float(a);
        lcnt++;
      }
    }
    wt[i] = o;
  }
#pragma unroll
  for (int off = 32; off > 0; off >>= 1) {
    lsum += __shfl_down(lsum, off);
    lcnt += __shfl_down(lcnt, off);
  }
  __shared__ float ssum[4];
  __shared__ unsigned int scnt[4];
  int wave = t >> 6, lane = t & 63;
  if (lane == 0) { ssum[wave] = lsum; scnt[wave] = lcnt; }
  __syncthreads();
  if (t == 0) {
    float fs = ssum[0] + ssum[1] + ssum[2] + ssum[3];
    unsigned int fc = scnt[0] + scnt[1] + scnt[2] + scnt[3];
    atomicAdd(&st->sum, fs);
    atomicAdd(&st->count, fc);
  }
}

__device__ __forceinline__ void async_copy16(const unsigned short* g, unsigned short* l) {
  __builtin_amdgcn_global_load_lds(
      (const __attribute__((address_space(1))) void*)g,
      (__attribute__((address_space(3))) void*)l, 16, 0, 0);
}

// 256x256-tile GEMM, BK=32, 4 rotating LDS buffers (128 KiB), counted-vmcnt
// pipeline: 3 tiles prefetched ahead, s_waitcnt vmcnt(8) per iteration (never
// drain to 0 in the main loop), one raw s_barrier per iteration.
//
// LDS XOR-swizzle (T2, both-sides involution per rule #21): without it, a
// quarter-wave's ds_read_b128 covers only 8 of 32 banks (bank group =
// 16*(row&1) + 4*quad) -> 8-way conflict, measured 2.5e7 conflict cycles.
// Store logical chunk l of row r at physical slot l ^ ((r>>1)&3) by
// pre-swizzling the GLOBAL source column (LDS dest stays linear, as
// global_load_lds requires); apply the same XOR on the ds_read address.
// Result: each 16-lane quarter covers all 32 banks exactly 2x (free).
// 8 waves (2Mx4N), 128x64 output per wave.
// C[m][n] = scale * sum_k A[m][k]*B[n][k] + bias[n].
__global__ __launch_bounds__(512, 2)
void gemm_kernel(const unsigned short* __restrict__ A,
                 const unsigned short* __restrict__ B,
                 const float* __restrict__ bias,
                 const SelState* __restrict__ st,
                 float* __restrict__ C, int N) {
  constexpr int K = IN_F;
  constexpr int NT = K / 32;  // 128 K-tiles
  __shared__ __align__(16) unsigned short As[4][256 * 32];
  __shared__ __align__(16) unsigned short Bs[4][256 * 32];

  const int tid = threadIdx.x;
  const int wave = tid >> 6, lane = tid & 63;
  const int wm = wave >> 2, wn = wave & 3;   // 2x4 wave grid
  const int l16 = lane & 15, quad = lane >> 4;

  const int rowBase = blockIdx.y * 256;
  const int colBase = blockIdx.x * 256;
  const unsigned short* Ag = A + (size_t)rowBase * K;
  const unsigned short* Bg = B + (size_t)colBase * K;

  // Staging: per tile 4 issues x 512 threads x 16B = 256 rows x 64 B.
  // Chunk id g: row g>>2, physical slot g&3 (LDS dest linear at g*16).
  // Source logical chunk = (g&3) ^ ((row>>1)&3), where (g>>3)&3 == (row>>1)&3.
  const int g0 = tid;
  const int g1 = 512 + tid;
  const int c0 = ((g0 & 3) ^ ((g0 >> 3) & 3)) * 8;
  const int c1 = ((g1 & 3) ^ ((g1 >> 3) & 3)) * 8;
  const unsigned short* pA0 = Ag + (size_t)(g0 >> 2) * K + c0;
  const unsigned short* pA1 = Ag + (size_t)(g1 >> 2) * K + c1;
  const unsigned short* pB0 = Bg + (size_t)(g0 >> 2) * K + c0;
  const unsigned short* pB1 = Bg + (size_t)(g1 >> 2) * K + c1;

  // Read side: fragment row = base + l16 with base % 16 == 0, so
  // ((base+l16)>>1)&3 == (l16>>1)&3. Physical chunk = quad ^ that.
  const int swz = (quad ^ ((l16 >> 1) & 3)) * 8;
  const int aoff = (wm * 128 + l16) * 32 + swz;
  const int boff = (wn * 64 + l16) * 32 + swz;

  f32x4 acc[8][4];
#pragma unroll
  for (int i = 0; i < 8; ++i)
#pragma unroll
    for (int j = 0; j < 4; ++j) acc[i][j] = {0.0f, 0.0f, 0.0f, 0.0f};

#define STAGE(buf, t) do {                                   \
    int ko = (t) * 32;                                       \
    async_copy16(pA0 + ko, &As[(buf)][g0 * 8]);              \
    async_copy16(pA1 + ko, &As[(buf)][g1 * 8]);              \
    async_copy16(pB0 + ko, &Bs[(buf)][g0 * 8]);              \
    async_copy16(pB1 + ko, &Bs[(buf)][g1 * 8]);              \
  } while (0)

  // KBODY: wait(tile t landed for THIS wave; my ds_reads of buf (u+3)&3 from
  // iter t-1 drained) -> barrier (now tile t landed for ALL waves, and buf
  // (u+3)&3 is not being read by anyone) -> prefetch tile t+3 into it ->
  // fragment ds_reads -> MFMA cluster under setprio(1).
#define KBODY(t, u, VMASM, DOSTAGE) do {                                        \
    asm volatile(VMASM ::: "memory");                                           \
    __builtin_amdgcn_s_barrier();                                               \
    asm volatile("" ::: "memory");                                              \
    if (DOSTAGE) STAGE(((u) + 3) & 3, (t) + 3);                                 \
    const unsigned short* Ab = As[(u)];                                         \
    const unsigned short* Bb = Bs[(u)];                                         \
    bf16x8 af[8];                                                               \
    bf16x8 bfr[4];                                                              \
    _Pragma("unroll")                                                           \
    for (int i = 0; i < 8; ++i)                                                 \
      af[i] = __builtin_bit_cast(bf16x8, *(const short8*)(Ab + aoff + i * 512));\
    _Pragma("unroll")                                                           \
    for (int j = 0; j < 4; ++j)                                                 \
      bfr[j] = __builtin_bit_cast(bf16x8, *(const short8*)(Bb + boff + j * 512));\
    __builtin_amdgcn_s_setprio(1);                                              \
    _Pragma("unroll")                                                           \
    for (int i = 0; i < 8; ++i)                                                 \
      _Pragma("unroll")                                                         \
      for (int j = 0; j < 4; ++j)                                               \
        acc[i][j] = __builtin_amdgcn_mfma_f32_16x16x32_bf16(af[i], bfr[j],      \
                                                            acc[i][j], 0, 0, 0);\
    __builtin_amdgcn_s_setprio(0);                                              \
  } while (0)

  // Prologue: 3 tiles in flight (12 outstanding loads per thread).
  STAGE(0, 0);
  STAGE(1, 1);
  STAGE(2, 2);

  // Steady state: 12 outstanding -> vmcnt(8) proves the oldest tile landed.
  for (int tt = 0; tt <= NT - 8; tt += 4) {
    KBODY(tt + 0, 0, "s_waitcnt vmcnt(8) lgkmcnt(0)", true);
    KBODY(tt + 1, 1, "s_waitcnt vmcnt(8) lgkmcnt(0)", true);
    KBODY(tt + 2, 2, "s_waitcnt vmcnt(8) lgkmcnt(0)", true);
    KBODY(tt + 3, 3, "s_waitcnt vmcnt(8) lgkmcnt(0)", true);
  }
  // Tail: stage last tile, then drain 8 -> 4 -> 0.
  KBODY(NT - 4, 0, "s_waitcnt vmcnt(8) lgkmcnt(0)", true);
  KBODY(NT - 3, 1, "s_waitcnt vmcnt(8) lgkmcnt(0)", false);
  KBODY(NT - 2, 2, "s_waitcnt vmcnt(4) lgkmcnt(0)", false);
  KBODY(NT - 1, 3, "s_waitcnt vmcnt(0) lgkmcnt(0)", false);

#undef KBODY
#undef STAGE

  // scale computed inline (replaces finalize_kernel; identical fp32 division).
  unsigned int cnt = st->count;
  float scale = st->sum / (float)(cnt ? cnt : 1u);
  float bv[4];
#pragma unroll
  for (int j = 0; j < 4; ++j) bv[j] = bias[colBase + wn * 64 + j * 16 + l16];
#pragma unroll
  for (int i = 0; i < 8; ++i) {
    int row0 = rowBase + wm * 128 + i * 16 + quad * 4;
#pragma unroll
    for (int j = 0; j < 4; ++j) {
      int col = colBase + wn * 64 + j * 16 + l16;
#pragma unroll
      for (int r = 0; r < 4; ++r) {
        C[(size_t)(row0 + r) * N + col] = scale * acc[i][j][r] + bv[j];
      }
    }
  }
}

extern "C" void kernel_launch(void* const* d_in, const int* in_sizes, int n_in,
                              void* d_out, int out_size, void* d_ws, size_t ws_size,
                              hipStream_t stream) {
  const float* x = (const float*)d_in[0];
  const float* w = (const float*)d_in[1];
  const float* bias = (const float*)d_in[2];
  float* out = (float*)d_out;
  const int K = IN_F, N = OUT_F;
  const int n_w = in_sizes[1];            // 4096*4096
  const int n_x = in_sizes[0];            // 4*2048*4096
  const int M = n_x / K;                  // 8192
  const unsigned int k = (unsigned int)(n_w / 2);  // int(n * 0.5), 1-indexed kth

  char* ws = (char*)d_ws;
  SelState* st = (SelState*)ws;
  unsigned short* wt = (unsigned short*)(ws + 65536);                              // 32 MB
  unsigned short* xb = (unsigned short*)(ws + 65536 + (size_t)N * K * 2);          // 64 MB

  hipLaunchKernelGGL(cast_x_kernel, dim3(4096), dim3(256), 0, stream,
                     (const float4*)x, (ushort4*)xb, n_x / 4, st, k);
  for (int r = 0; r < 3; ++r) {
    hipLaunchKernelGGL(hist_kernel, dim3(1024), dim3(256), 0, stream,
                       (const float4*)w, n_w / 4, st, r);
    hipLaunchKernelGGL(scan_kernel, dim3(1), dim3(256), 0, stream, st, r);
  }
  hipLaunchKernelGGL(quant_kernel, dim3(1024), dim3(256), 0, stream,
                     (const float4*)w, (ushort4*)wt, n_w / 4, st);
  hipLaunchKernelGGL(gemm_kernel, dim3(N / 256, M / 256), dim3(512), 0, stream,
                     xb, wt, bias, st, out, N);
}